// Round 1
// baseline (13247.392 us; speedup 1.0000x reference)
//
#include <hip/hip_runtime.h>
#include <cstdint>
#include <cstddef>

#define WIDTH 4096
#define DEPTH 512
#define NHIST 20
#define NS 64

typedef __attribute__((ext_vector_type(4))) float f32x4;
typedef __attribute__((ext_vector_type(8))) short bf16x8;

__device__ __forceinline__ ushort f2bf(float f) {
    uint32_t u = __float_as_uint(f);
    u += 0x7FFFu + ((u >> 16) & 1u);   // round-to-nearest-even
    return (ushort)(u >> 16);
}

// ---------------- W fp32 -> bf16 (RNE) ----------------
__global__ __launch_bounds__(256) void convert_w_kernel(const float* __restrict__ W,
                                                        ushort* __restrict__ Wb) {
    size_t i = ((size_t)blockIdx.x * 256 + threadIdx.x) * 8;
    float4 f0 = *(const float4*)(W + i);
    float4 f1 = *(const float4*)(W + i + 4);
    ushort4 u0, u1;
    u0.x = f2bf(f0.x); u0.y = f2bf(f0.y); u0.z = f2bf(f0.z); u0.w = f2bf(f0.w);
    u1.x = f2bf(f1.x); u1.y = f2bf(f1.y); u1.z = f2bf(f1.z); u1.w = f2bf(f1.w);
    *(ushort4*)(Wb + i)     = u0;
    *(ushort4*)(Wb + i + 4) = u1;
}

// ---------------- curr0 = tile(x) in bf16 ----------------
__global__ __launch_bounds__(256) void init_curr_kernel(const float* __restrict__ x,
                                                        ushort* __restrict__ cur) {
    int s = blockIdx.x;
    for (int i = threadIdx.x; i < WIDTH; i += 256)
        cur[(size_t)s * WIDTH + i] = f2bf(x[i]);
}

// ---------------- bias GEMM, fp32 vector ALU ----------------
// C[n][i] = dot(biases[n,:], W_bias[i,:])   n in [0,512), i in [0,4096)
__global__ __launch_bounds__(256) void bias_gemm_kernel(const float* __restrict__ A,   // biases [512][4096]
                                                        const float* __restrict__ B,   // W_bias [4096][4096]
                                                        float* __restrict__ C) {       // b [512][4096]
    __shared__ float As[64][36];
    __shared__ float Bs[64][36];
    const int bm = blockIdx.y;          // 0..7
    const int bn = blockIdx.x;          // 0..63
    const int t  = threadIdx.x;
    const int tx = t & 15, ty = t >> 4; // 16x16 thread grid, 4x4 per thread
    const int lr = t >> 3;              // loader row 0..31
    const int lc = (t & 7) * 4;         // loader col (float4)

    float acc[4][4] = {};
    for (int k0 = 0; k0 < WIDTH; k0 += 32) {
        float4 a0 = *(const float4*)&A[(size_t)(bm * 64 + lr) * WIDTH + k0 + lc];
        float4 a1 = *(const float4*)&A[(size_t)(bm * 64 + lr + 32) * WIDTH + k0 + lc];
        float4 b0 = *(const float4*)&B[(size_t)(bn * 64 + lr) * WIDTH + k0 + lc];
        float4 b1 = *(const float4*)&B[(size_t)(bn * 64 + lr + 32) * WIDTH + k0 + lc];
        __syncthreads();
        *(float4*)&As[lr][lc] = a0;  *(float4*)&As[lr + 32][lc] = a1;
        *(float4*)&Bs[lr][lc] = b0;  *(float4*)&Bs[lr + 32][lc] = b1;
        __syncthreads();
        #pragma unroll
        for (int k = 0; k < 32; k += 4) {
            float4 av[4], bv[4];
            #pragma unroll
            for (int mi = 0; mi < 4; mi++) av[mi] = *(const float4*)&As[ty * 4 + mi][k];
            #pragma unroll
            for (int ni = 0; ni < 4; ni++) bv[ni] = *(const float4*)&Bs[tx * 4 + ni][k];
            #pragma unroll
            for (int mi = 0; mi < 4; mi++)
                #pragma unroll
                for (int ni = 0; ni < 4; ni++)
                    acc[mi][ni] += av[mi].x * bv[ni].x + av[mi].y * bv[ni].y +
                                   av[mi].z * bv[ni].z + av[mi].w * bv[ni].w;
        }
    }
    #pragma unroll
    for (int mi = 0; mi < 4; mi++) {
        float4 v = make_float4(acc[mi][0], acc[mi][1], acc[mi][2], acc[mi][3]);
        *(float4*)&C[(size_t)(bm * 64 + ty * 4 + mi) * WIDTH + bn * 64 + tx * 4] = v;
    }
}

// ---------------- one recurrence step ----------------
// out[s, n] = erf(scale[s] * dot(cur_in[s,:], W[n,:]) + brow[n]) / 64
// grid 128 WGs (N-tile 32), 8 waves/WG (K-split 512 each), mfma 16x16x32 bf16
__global__ __launch_bounds__(512) void step_kernel(const ushort* __restrict__ cur_in,
                                                   ushort* __restrict__ cur_out,
                                                   const ushort* __restrict__ Wb,
                                                   const float* __restrict__ brow,
                                                   const float* __restrict__ scales,
                                                   float* __restrict__ out_hist,
                                                   int hist_h) {
    __shared__ float partial[8][64][32];   // 64 KB
    const int t    = threadIdx.x;
    const int wave = t >> 6;
    const int lane = t & 63;
    const int lrow = lane & 15;   // row within 16-block (A-m / B-n)
    const int lq   = lane >> 4;   // quad: k = lq*8 + j
    const int n0   = blockIdx.x * 32;

    const ushort* ap = cur_in + (size_t)lrow * WIDTH + wave * 512 + lq * 8;
    const ushort* bp = Wb + (size_t)(n0 + lrow) * WIDTH + wave * 512 + lq * 8;

    f32x4 acc[4][2] = {};
    #pragma unroll 2
    for (int kk = 0; kk < 512; kk += 32) {
        bf16x8 af[4], bfr[2];
        #pragma unroll
        for (int mb = 0; mb < 4; mb++)
            af[mb] = *(const bf16x8*)(ap + (size_t)mb * 16 * WIDTH + kk);
        #pragma unroll
        for (int nb = 0; nb < 2; nb++)
            bfr[nb] = *(const bf16x8*)(bp + (size_t)nb * 16 * WIDTH + kk);
        #pragma unroll
        for (int mb = 0; mb < 4; mb++)
            #pragma unroll
            for (int nb = 0; nb < 2; nb++)
                acc[mb][nb] = __builtin_amdgcn_mfma_f32_16x16x32_bf16(af[mb], bfr[nb], acc[mb][nb], 0, 0, 0);
    }

    // C/D layout: col = lane&15, row = (lane>>4)*4 + reg   [measured m89/m91]
    #pragma unroll
    for (int mb = 0; mb < 4; mb++)
        #pragma unroll
        for (int nb = 0; nb < 2; nb++)
            #pragma unroll
            for (int r = 0; r < 4; r++)
                partial[wave][mb * 16 + lq * 4 + r][nb * 16 + lrow] = acc[mb][nb][r];
    __syncthreads();

    // epilogue: 64x32 outputs over 512 threads -> 4 each
    const int s  = t >> 3;
    const int nn = (t & 7) * 4;
    const float sc = scales[s];
    float vals[4];
    #pragma unroll
    for (int j = 0; j < 4; j++) {
        float sum = 0.f;
        #pragma unroll
        for (int w = 0; w < 8; w++) sum += partial[w][s][nn + j];
        float pre = sc * sum + brow[n0 + nn + j];
        vals[j] = erff(pre) * 0.015625f;   // 1/sqrt(4096)
    }
    ushort4 uv;
    uv.x = f2bf(vals[0]); uv.y = f2bf(vals[1]); uv.z = f2bf(vals[2]); uv.w = f2bf(vals[3]);
    *(ushort4*)(cur_out + (size_t)s * WIDTH + n0 + nn) = uv;
    if (hist_h >= 0) {
        float4 fv = make_float4(vals[0], vals[1], vals[2], vals[3]);
        *(float4*)(out_hist + ((size_t)s * NHIST + hist_h) * WIDTH + n0 + nn) = fv;
    }
}

extern "C" void kernel_launch(void* const* d_in, const int* in_sizes, int n_in,
                              void* d_out, int out_size, void* d_ws, size_t ws_size,
                              hipStream_t stream) {
    const float* x       = (const float*)d_in[0];
    const float* biases  = (const float*)d_in[1];
    const float* W       = (const float*)d_in[2];
    const float* W_bias  = (const float*)d_in[3];
    const float* scales  = (const float*)d_in[4];
    float* out = (float*)d_out;

    char* ws = (char*)d_ws;
    ushort* Wbf = (ushort*)ws;                                  // 32 MB
    float*  b   = (float*)(ws + (size_t)32 * 1024 * 1024);      // 8 MB
    ushort* cur0 = (ushort*)(ws + (size_t)40 * 1024 * 1024);    // 512 KB
    ushort* cur1 = cur0 + (size_t)NS * WIDTH;                   // 512 KB

    convert_w_kernel<<<8192, 256, 0, stream>>>(W, Wbf);
    init_curr_kernel<<<NS, 256, 0, stream>>>(x, cur0);
    bias_gemm_kernel<<<dim3(64, 8), 256, 0, stream>>>(biases, W_bias, b);

    for (int d = 0; d < DEPTH; d++) {
        ushort* cin  = (d & 1) ? cur1 : cur0;
        ushort* cout = (d & 1) ? cur0 : cur1;
        int h = d - (DEPTH - NHIST);
        if (h < 0) h = -1;
        step_kernel<<<128, 512, 0, stream>>>(cin, cout, Wbf, b + (size_t)d * WIDTH,
                                             scales, out, h);
    }
}